// Round 10
// baseline (200.999 us; speedup 1.0000x reference)
//
#include <hip/hip_runtime.h>

#define EPSF 1e-10f

constexpr unsigned KEY15 = 0xBFC00000u;  // f2key(1.5f), bucket-aligned
constexpr int BUCK0 = 0xBFC;             // first tracked bucket (3068)
constexpr int NB2   = 4096 - BUCK0;      // 1028 tracked buckets
constexpr int NBKT  = 4096;
constexpr int NREP  = 32;                // replica rows for flush
constexpr int CHUNK = 2048;              // staged elements per chunk

// ---------- workspace layout (words) ----------
// sc: 0 np(u32) 1 psig(f32) 2 plos(f32) 3 k(u32) 7 flag(u32)
constexpr int SC_OFF    = 0;
constexpr int BSTAT_OFF = 64;                       // 4096 float4 (16384 words)
constexpr int REP_OFF   = BSTAT_OFF + 4096 * 4;     // 16448
constexpr int LOW_OFF   = REP_OFF + NREP * NB2;     // 49344 (fallback hist)
constexpr int ZERO_WORDS = LOW_OFF + NBKT;          // 53440

__device__ __forceinline__ float sigmoidf_(float x) {
    return 1.0f / (1.0f + expf(-x));
}
__device__ __forceinline__ float softplusf_(float x) {
    return fmaxf(x, 0.0f) + log1pf(expf(-fabsf(x)));
}
__device__ __forceinline__ unsigned f2key(float x) {
    unsigned b = __float_as_uint(x);
    return b ^ ((unsigned)((int)b >> 31) | 0x80000000u);
}
__device__ __forceinline__ float key2f(unsigned k) {
    unsigned b = (k & 0x80000000u) ? (k & 0x7FFFFFFFu) : ~k;
    return __uint_as_float(b);
}

// async global->LDS, 16B per lane; dest = wave-uniform base + lane*16
__device__ __forceinline__ void gload_lds16(const void* g, void* l) {
    __builtin_amdgcn_global_load_lds(
        (const __attribute__((address_space(1))) unsigned*)g,
        (__attribute__((address_space(3))) unsigned*)l, 16, 0, 0);
}

// ---------------------------------------------------------------------------
__global__ void zeroAll(unsigned* ws, int nwords) {
    int stride = gridDim.x * blockDim.x;
    for (int i = blockIdx.x * blockDim.x + threadIdx.x; i < nwords; i += stride)
        ws[i] = 0u;
}

// K1: double-buffered global_load_lds staging (zero data VGPRs -> deep MLP
// the register allocator can't collapse), branchy consume out of LDS.
__global__ __launch_bounds__(256) void k1(const float* __restrict__ preds,
                                          const int* __restrict__ targs, int N,
                                          float4* __restrict__ bstat,
                                          unsigned* __restrict__ rep) {
    __shared__ float bp[2][CHUNK];
    __shared__ int   bt[2][CHUNK];
    __shared__ int   lh[NB2];
    for (int i = threadIdx.x; i < NB2; i += 256) lh[i] = 0;
    __syncthreads();

    float pc = 0.f, psig = 0.f, plos = 0.f;
    const int tid = threadIdx.x;
    const int w = tid >> 6;                  // wave id (LDS base must be wave-uniform)

    int nfull = N >> 11;                     // CHUNK-sized chunks
    int cpb = (nfull + gridDim.x - 1) / gridDim.x;
    int c0 = blockIdx.x * cpb;
    int c1 = c0 + cpb; if (c1 > nfull) c1 = nfull;
    int nloc = c1 - c0;

    if (nloc > 0) {
        // stage chunk c into buffer b (4 x 16B async loads per thread)
        auto stage = [&](int b, int c) {
            const float* gp = preds + ((size_t)c << 11);
            const int*   gt = targs + ((size_t)c << 11);
#pragma unroll
            for (int r = 0; r < 2; r++) {
                int goff = r * 1024 + tid * 4;        // this lane's element offset
                int loff = r * 1024 + w * 256;        // wave-uniform dest (HW adds lane*16)
                gload_lds16(gp + goff, &bp[b][loff]);
                gload_lds16(gt + goff, &bt[b][loff]);
            }
        };
        stage(0, c0);
        for (int i = 0; i < nloc; i++) {
            int cur = i & 1;
            __syncthreads();                 // drains vmcnt -> buf[cur] ready; also
                                             // guards buffer reuse across iterations
            if (i + 1 < nloc) stage(1 - cur, c0 + i + 1);   // in flight during consume
#pragma unroll
            for (int e = 0; e < CHUNK / 256; e++) {
                int idx = tid + (e << 8);    // stride-256: conflict-free b32 reads
                float x = bp[cur][idx];
                int   t = bt[cur][idx];
                unsigned key = f2key(x);
                if ((t == 0) && (key >= KEY15))
                    atomicAdd(&lh[(key >> 20) - BUCK0], 1);   // fire-and-forget ds_add
                if (t) { pc += 1.f; psig += sigmoidf_(x); plos += softplusf_(x) - x; }
            }
        }
    }
    // tail elements (N % CHUNK), last block only
    if (blockIdx.x == gridDim.x - 1) {
        for (int i = (nfull << 11) + tid; i < N; i += 256) {
            float x = preds[i];
            if (targs[i]) { pc += 1.f; psig += sigmoidf_(x); plos += softplusf_(x) - x; }
            else {
                unsigned key = f2key(x);
                if (key >= KEY15) atomicAdd(&lh[(key >> 20) - BUCK0], 1);
            }
        }
    }
    __syncthreads();
    unsigned* my = rep + (unsigned)(blockIdx.x & (NREP - 1)) * NB2;
    for (int i = tid; i < NB2; i += 256) {
        int c = lh[i];
        if (c) atomicAdd(&my[i], (unsigned)c);
    }
#pragma unroll
    for (int o = 32; o > 0; o >>= 1) {
        pc   += __shfl_down(pc, o);
        psig += __shfl_down(psig, o);
        plos += __shfl_down(plos, o);
    }
    __shared__ float rp[4], rs[4], rl[4];
    if ((tid & 63) == 0) { rp[w] = pc; rs[w] = psig; rl[w] = plos; }
    __syncthreads();
    if (tid == 0)
        bstat[blockIdx.x] = make_float4(rp[0] + rp[1] + rp[2] + rp[3],
                                        rs[0] + rs[1] + rs[2] + rs[3],
                                        rl[0] + rl[1] + rl[2] + rl[3], 0.f);
}

// flagK: reduce per-block stats -> np, psig, plos, k; replica total ->
// fallback flag if k exceeds qualifying-negative count.
__global__ void flagK(const float4* __restrict__ bstat, int nblocks,
                      const unsigned* __restrict__ rep,
                      unsigned* __restrict__ sc, unsigned N) {
    float pc = 0.f, ps = 0.f, pl = 0.f;
    for (int i = threadIdx.x; i < nblocks; i += 256) {
        float4 v = bstat[i];
        pc += v.x; ps += v.y; pl += v.z;
    }
    unsigned qt = 0;
    for (int i = threadIdx.x; i < NREP * NB2; i += 256) qt += rep[i];
#pragma unroll
    for (int o = 32; o > 0; o >>= 1) {
        pc += __shfl_down(pc, o);
        ps += __shfl_down(ps, o);
        pl += __shfl_down(pl, o);
        qt += __shfl_down(qt, o);
    }
    __shared__ float rp[4], rs[4], rl[4];
    __shared__ unsigned rq[4];
    int w = threadIdx.x >> 6;
    if ((threadIdx.x & 63) == 0) { rp[w] = pc; rs[w] = ps; rl[w] = pl; rq[w] = qt; }
    __syncthreads();
    if (threadIdx.x == 0) {
        unsigned np = (unsigned)(rp[0] + rp[1] + rp[2] + rp[3] + 0.5f);
        float psT = rs[0] + rs[1] + rs[2] + rs[3];
        float plT = rl[0] + rl[1] + rl[2] + rl[3];
        unsigned qtT = rq[0] + rq[1] + rq[2] + rq[3];
        unsigned nn = N - np;
        unsigned k = (np == 0u) ? (unsigned)(0.1 * (double)nn)
                                : ((30u * np < nn) ? 30u * np : nn);
        float* scf = (float*)sc;
        sc[0] = np; scf[1] = psT; scf[2] = plT; sc[3] = k;
        sc[7] = (k > qtT) ? 1u : 0u;
    }
}

// Fallback (flag only): histogram negatives with key < KEY15. Normally exits.
__global__ __launch_bounds__(256) void lowH(const float* __restrict__ preds,
                                            const int* __restrict__ targs, int N,
                                            const unsigned* __restrict__ sc,
                                            unsigned* __restrict__ low) {
    if (sc[7] == 0u) return;
    int gtid = blockIdx.x * 256 + threadIdx.x;
    int gstr = gridDim.x * 256;
    for (int i = gtid; i < N; i += gstr) {
        if (!targs[i]) {
            unsigned key = f2key(preds[i]);
            if (key < KEY15) atomicAdd(&low[key >> 20], 1u);
        }
    }
}

// finalize: counts = replicas (>= BUCK0) + low hist (< BUCK0, flag path);
// suffix-scan -> b1/r1; analytic bucket-midpoint sums; dice + mean.
__global__ void finalize(const unsigned* __restrict__ rep,
                         const unsigned* __restrict__ low,
                         unsigned* __restrict__ sc, float* __restrict__ out) {
    __shared__ unsigned sa[256], sb[256];
    __shared__ int sb1;
    __shared__ unsigned sr1;
    __shared__ double dsig[256], dsp[256];
    int t = threadIdx.x;
    int base = t * 16;
    unsigned c[16]; unsigned tot = 0;
#pragma unroll
    for (int j = 0; j < 16; j++) {
        int b = base + j;
        unsigned s;
        if (b >= BUCK0) {
            s = 0;
            int idx = b - BUCK0;
#pragma unroll 8
            for (int r = 0; r < NREP; r++) s += rep[r * NB2 + idx];
        } else {
            s = low[b];
        }
        c[j] = s; tot += s;
    }
    sa[t] = tot;
    if (t == 0) { sb1 = NBKT; sr1 = 0u; }
    __syncthreads();
    unsigned k = sc[3];
    unsigned* src = sa; unsigned* dst = sb;
    for (int off = 1; off < 256; off <<= 1) {
        unsigned v = src[t] + ((t + off < 256) ? src[t + off] : 0u);
        dst[t] = v;
        __syncthreads();
        unsigned* tmp = src; src = dst; dst = tmp;
    }
    if (k > 0u) {
        unsigned above = src[t] - tot;
        if (above < k && above + tot >= k) {
            unsigned cum = above;
            for (int j = 15; j >= 0; j--) {
                unsigned cc = c[j];
                if (cum + cc >= k) { sb1 = base + j; sr1 = k - cum; break; }
                cum += cc;
            }
        }
    }
    __syncthreads();
    int b1 = sb1; unsigned r1 = sr1;
    double ssig = 0.0, ssp = 0.0;
#pragma unroll
    for (int j = 0; j < 16; j++) {
        int b = base + j; unsigned cc = c[j];
        if (cc == 0u) continue;
        bool full = (b > b1);
        bool part = (b == b1) && (r1 > 0u);
        if (!(full || part)) continue;
        float lo = key2f((unsigned)b << 20);
        float hi = (b == NBKT - 1) ? key2f(0xFF7FFFFFu)
                                   : key2f(((unsigned)(b + 1)) << 20);
        if (full) {
            float mid = 0.5f * (lo + hi);
            ssig += (double)cc * (double)sigmoidf_(mid);
            ssp  += (double)cc * (double)softplusf_(mid);
        } else {
            unsigned take = (r1 < cc) ? r1 : cc;
            double q = (double)take / (double)cc;
            float rp = (float)((double)hi - 0.5 * q * ((double)hi - (double)lo));
            ssig += (double)take * (double)sigmoidf_(rp);
            ssp  += (double)take * (double)softplusf_(rp);
        }
    }
    dsig[t] = ssig; dsp[t] = ssp;
    __syncthreads();
    if (t == 0) {
        double sns = 0.0, snl = 0.0;
        for (int i = 0; i < 256; i++) { sns += dsig[i]; snl += dsp[i]; }
        float* scf = (float*)sc;
        unsigned np = sc[0];
        float psig = scf[1], plos = scf[2];
        double denom = (double)psig + sns + (double)np;
        double dice = 1.0 - (2.0 * (double)psig + (double)EPSF) / (denom + (double)EPSF);
        unsigned totsel = np + k;
        double mean = totsel ? (((double)plos + snl) / (double)totsel) : 0.0;
        out[0] = (float)(dice + mean);
    }
}

// ---------------------------------------------------------------------------
extern "C" void kernel_launch(void* const* d_in, const int* in_sizes, int n_in,
                              void* d_out, int out_size, void* d_ws, size_t ws_size,
                              hipStream_t stream) {
    const float* preds = (const float*)d_in[0];
    const int*   targs = (const int*)d_in[1];
    float* out = (float*)d_out;
    int N = in_sizes[0];

    unsigned* ws    = (unsigned*)d_ws;
    unsigned* sc    = ws + SC_OFF;
    float4*   bstat = (float4*)(ws + BSTAT_OFF);
    unsigned* rep   = ws + REP_OFF;
    unsigned* low   = ws + LOW_OFF;

    int grid = 2048;   // 8 blocks/CU nominal; LDS (36KB) caps residency at 4/CU

    zeroAll<<<64, 256, 0, stream>>>(ws, ZERO_WORDS);
    k1<<<grid, 256, 0, stream>>>(preds, targs, N, bstat, rep);
    flagK<<<1, 256, 0, stream>>>(bstat, grid, rep, sc, (unsigned)N);
    lowH<<<512, 256, 0, stream>>>(preds, targs, N, sc, low);
    finalize<<<1, 256, 0, stream>>>(rep, low, sc, out);
}

// Round 11
// 169.841 us; speedup vs baseline: 1.1835x; 1.1835x over previous
//
#include <hip/hip_runtime.h>

#define EPSF 1e-10f

constexpr unsigned KEY15 = 0xBFC00000u;  // f2key(1.5f), bucket-aligned
constexpr int BUCK0 = 0xBFC;             // first tracked bucket (3068)
constexpr int NB2   = 4096 - BUCK0;      // 1028 tracked buckets
constexpr int NBKT  = 4096;
constexpr int NREP  = 8;                 // replica rows for flush

typedef float pf4 __attribute__((ext_vector_type(4)));
typedef int   pi4 __attribute__((ext_vector_type(4)));

// ---------- workspace layout (words) ----------
// sc: 0 np(u32) 1 psig(f32) 2 plos(f32) 3 k(u32) 7 flag(u32)
constexpr int SC_OFF    = 0;
constexpr int BSTAT_OFF = 64;                       // 4096 float4 (16384 words)
constexpr int REP_OFF   = BSTAT_OFF + 4096 * 4;     // 16448
constexpr int LOW_OFF   = REP_OFF + NREP * NB2;     // 24672 (fallback hist)
constexpr int ZERO_WORDS = LOW_OFF + NBKT;          // 28768

__device__ __forceinline__ float sigmoidf_(float x) {
    return 1.0f / (1.0f + expf(-x));
}
__device__ __forceinline__ float softplusf_(float x) {
    return fmaxf(x, 0.0f) + log1pf(expf(-fabsf(x)));
}
__device__ __forceinline__ unsigned f2key(float x) {
    unsigned b = __float_as_uint(x);
    return b ^ ((unsigned)((int)b >> 31) | 0x80000000u);
}
__device__ __forceinline__ float key2f(unsigned k) {
    unsigned b = (k & 0x80000000u) ? (k & 0x7FFFFFFFu) : ~k;
    return __uint_as_float(b);
}

// ---------------------------------------------------------------------------
__global__ void zeroAll(unsigned* ws, int nwords) {
    int stride = gridDim.x * blockDim.x;
    for (int i = blockIdx.x * blockDim.x + threadIdx.x; i < nwords; i += stride)
        ws[i] = 0u;
}

// K1: 8192 elements per block-tile. A SINGLE asm block issues 16 independent
// global_load_dwordx4 (early-clobber outputs -> 64 data VGPRs the allocator
// cannot recycle) then s_waitcnt vmcnt(0). This forces the memory-level
// parallelism the compiler kept collapsing (rounds 8-10: VGPR pinned at 48).
__global__ __launch_bounds__(256) void k1(const float* __restrict__ preds,
                                          const int* __restrict__ targs, int N,
                                          float4* __restrict__ bstat,
                                          unsigned* __restrict__ rep) {
    __shared__ int lh[NB2];
    for (int i = threadIdx.x; i < NB2; i += 256) lh[i] = 0;
    __syncthreads();

    float pc = 0.f, psig = 0.f, plos = 0.f;
    const int tid = threadIdx.x;
    const int lane = tid & 63;
    const int w = tid >> 6;

    int nfull = N >> 13;                     // full 8192-element tiles
    for (int grp = blockIdx.x; grp < nfull; grp += gridDim.x) {
        size_t ebase = ((size_t)grp << 13) + ((size_t)w << 11) + ((size_t)lane << 2);
        const float* pp  = preds + ebase;        // wave tile: 2048 elements
        const float* pp2 = pp + 1024;
        const int*   tp  = targs + ebase;
        const int*   tp2 = tp + 1024;
        pf4 P[8]; pi4 T[8];
        asm volatile(
            "global_load_dwordx4 %0, %16, off\n\t"
            "global_load_dwordx4 %1, %16, off offset:1024\n\t"
            "global_load_dwordx4 %2, %16, off offset:2048\n\t"
            "global_load_dwordx4 %3, %16, off offset:3072\n\t"
            "global_load_dwordx4 %4, %17, off\n\t"
            "global_load_dwordx4 %5, %17, off offset:1024\n\t"
            "global_load_dwordx4 %6, %17, off offset:2048\n\t"
            "global_load_dwordx4 %7, %17, off offset:3072\n\t"
            "global_load_dwordx4 %8, %18, off\n\t"
            "global_load_dwordx4 %9, %18, off offset:1024\n\t"
            "global_load_dwordx4 %10, %18, off offset:2048\n\t"
            "global_load_dwordx4 %11, %18, off offset:3072\n\t"
            "global_load_dwordx4 %12, %19, off\n\t"
            "global_load_dwordx4 %13, %19, off offset:1024\n\t"
            "global_load_dwordx4 %14, %19, off offset:2048\n\t"
            "global_load_dwordx4 %15, %19, off offset:3072\n\t"
            "s_waitcnt vmcnt(0)"
            : "=&v"(P[0]), "=&v"(P[1]), "=&v"(P[2]), "=&v"(P[3]),
              "=&v"(P[4]), "=&v"(P[5]), "=&v"(P[6]), "=&v"(P[7]),
              "=&v"(T[0]), "=&v"(T[1]), "=&v"(T[2]), "=&v"(T[3]),
              "=&v"(T[4]), "=&v"(T[5]), "=&v"(T[6]), "=&v"(T[7])
            : "v"(pp), "v"(pp2), "v"(tp), "v"(tp2)
            : "memory");
#pragma unroll
        for (int g = 0; g < 8; g++) {
            pf4 pv = P[g]; pi4 tv = T[g];
#pragma unroll
            for (int j = 0; j < 4; j++) {
                float x = pv[j];
                unsigned key = f2key(x);
                if ((tv[j] == 0) && (key >= KEY15))
                    atomicAdd(&lh[(key >> 20) - BUCK0], 1);   // fire-and-forget ds_add
            }
            if (tv[0] | tv[1] | tv[2] | tv[3]) {   // rare positive path
#pragma unroll
                for (int j = 0; j < 4; j++)
                    if (tv[j]) {
                        float x = pv[j];
                        pc += 1.f; psig += sigmoidf_(x); plos += softplusf_(x) - x;
                    }
            }
        }
    }
    // tail elements (N % 8192), last block only
    if (blockIdx.x == gridDim.x - 1) {
        for (int i = (nfull << 13) + tid; i < N; i += 256) {
            float x = preds[i];
            if (targs[i]) { pc += 1.f; psig += sigmoidf_(x); plos += softplusf_(x) - x; }
            else {
                unsigned key = f2key(x);
                if (key >= KEY15) atomicAdd(&lh[(key >> 20) - BUCK0], 1);
            }
        }
    }
    __syncthreads();
    // flush hist + accumulate this block's qualifying count
    float qc = 0.f;
    unsigned* my = rep + (unsigned)(blockIdx.x & (NREP - 1)) * NB2;
    for (int i = tid; i < NB2; i += 256) {
        int c = lh[i];
        if (c) { atomicAdd(&my[i], (unsigned)c); qc += (float)c; }
    }
#pragma unroll
    for (int o = 32; o > 0; o >>= 1) {
        pc   += __shfl_down(pc, o);
        psig += __shfl_down(psig, o);
        plos += __shfl_down(plos, o);
        qc   += __shfl_down(qc, o);
    }
    __shared__ float rp[4], rs[4], rl[4], rq[4];
    if ((tid & 63) == 0) { rp[w] = pc; rs[w] = psig; rl[w] = plos; rq[w] = qc; }
    __syncthreads();
    if (tid == 0)
        bstat[blockIdx.x] = make_float4(rp[0] + rp[1] + rp[2] + rp[3],
                                        rs[0] + rs[1] + rs[2] + rs[3],
                                        rl[0] + rl[1] + rl[2] + rl[3],
                                        rq[0] + rq[1] + rq[2] + rq[3]);
}

// flagK: reduce per-block stats (including qualifying count in .w) -> np,
// psig, plos, k, fallback flag. Only reads bstat (32 KB).
__global__ void flagK(const float4* __restrict__ bstat, int nblocks,
                      unsigned* __restrict__ sc, unsigned N) {
    float pc = 0.f, ps = 0.f, pl = 0.f, qt = 0.f;
    for (int i = threadIdx.x; i < nblocks; i += 256) {
        float4 v = bstat[i];
        pc += v.x; ps += v.y; pl += v.z; qt += v.w;
    }
#pragma unroll
    for (int o = 32; o > 0; o >>= 1) {
        pc += __shfl_down(pc, o);
        ps += __shfl_down(ps, o);
        pl += __shfl_down(pl, o);
        qt += __shfl_down(qt, o);
    }
    __shared__ float rp[4], rs[4], rl[4], rq[4];
    int w = threadIdx.x >> 6;
    if ((threadIdx.x & 63) == 0) { rp[w] = pc; rs[w] = ps; rl[w] = pl; rq[w] = qt; }
    __syncthreads();
    if (threadIdx.x == 0) {
        unsigned np = (unsigned)(rp[0] + rp[1] + rp[2] + rp[3] + 0.5f);
        float psT = rs[0] + rs[1] + rs[2] + rs[3];
        float plT = rl[0] + rl[1] + rl[2] + rl[3];
        unsigned qtT = (unsigned)(rq[0] + rq[1] + rq[2] + rq[3] + 0.5f);
        unsigned nn = N - np;
        unsigned k = (np == 0u) ? (unsigned)(0.1 * (double)nn)
                                : ((30u * np < nn) ? 30u * np : nn);
        float* scf = (float*)sc;
        sc[0] = np; scf[1] = psT; scf[2] = plT; sc[3] = k;
        sc[7] = (k > qtT) ? 1u : 0u;
    }
}

// Fallback (flag only): histogram negatives with key < KEY15. Normally exits.
__global__ __launch_bounds__(256) void lowH(const float* __restrict__ preds,
                                            const int* __restrict__ targs, int N,
                                            const unsigned* __restrict__ sc,
                                            unsigned* __restrict__ low) {
    if (sc[7] == 0u) return;
    int gtid = blockIdx.x * 256 + threadIdx.x;
    int gstr = gridDim.x * 256;
    for (int i = gtid; i < N; i += gstr) {
        if (!targs[i]) {
            unsigned key = f2key(preds[i]);
            if (key < KEY15) atomicAdd(&low[key >> 20], 1u);
        }
    }
}

// finalize: counts = replicas (>= BUCK0) + low hist (< BUCK0, flag path);
// suffix-scan -> b1/r1; analytic bucket-midpoint sums; dice + mean.
__global__ void finalize(const unsigned* __restrict__ rep,
                         const unsigned* __restrict__ low,
                         unsigned* __restrict__ sc, float* __restrict__ out) {
    __shared__ unsigned sa[256], sb[256];
    __shared__ int sb1;
    __shared__ unsigned sr1;
    __shared__ double dsig[256], dsp[256];
    int t = threadIdx.x;
    int base = t * 16;
    unsigned c[16]; unsigned tot = 0;
#pragma unroll
    for (int j = 0; j < 16; j++) {
        int b = base + j;
        unsigned s;
        if (b >= BUCK0) {
            s = 0;
            int idx = b - BUCK0;
#pragma unroll
            for (int r = 0; r < NREP; r++) s += rep[r * NB2 + idx];
        } else {
            s = low[b];
        }
        c[j] = s; tot += s;
    }
    sa[t] = tot;
    if (t == 0) { sb1 = NBKT; sr1 = 0u; }
    __syncthreads();
    unsigned k = sc[3];
    unsigned* src = sa; unsigned* dst = sb;
    for (int off = 1; off < 256; off <<= 1) {
        unsigned v = src[t] + ((t + off < 256) ? src[t + off] : 0u);
        dst[t] = v;
        __syncthreads();
        unsigned* tmp = src; src = dst; dst = tmp;
    }
    if (k > 0u) {
        unsigned above = src[t] - tot;
        if (above < k && above + tot >= k) {
            unsigned cum = above;
            for (int j = 15; j >= 0; j--) {
                unsigned cc = c[j];
                if (cum + cc >= k) { sb1 = base + j; sr1 = k - cum; break; }
                cum += cc;
            }
        }
    }
    __syncthreads();
    int b1 = sb1; unsigned r1 = sr1;
    double ssig = 0.0, ssp = 0.0;
#pragma unroll
    for (int j = 0; j < 16; j++) {
        int b = base + j; unsigned cc = c[j];
        if (cc == 0u) continue;
        bool full = (b > b1);
        bool part = (b == b1) && (r1 > 0u);
        if (!(full || part)) continue;
        float lo = key2f((unsigned)b << 20);
        float hi = (b == NBKT - 1) ? key2f(0xFF7FFFFFu)
                                   : key2f(((unsigned)(b + 1)) << 20);
        if (full) {
            float mid = 0.5f * (lo + hi);
            ssig += (double)cc * (double)sigmoidf_(mid);
            ssp  += (double)cc * (double)softplusf_(mid);
        } else {
            unsigned take = (r1 < cc) ? r1 : cc;
            double q = (double)take / (double)cc;
            float rp = (float)((double)hi - 0.5 * q * ((double)hi - (double)lo));
            ssig += (double)take * (double)sigmoidf_(rp);
            ssp  += (double)take * (double)softplusf_(rp);
        }
    }
    dsig[t] = ssig; dsp[t] = ssp;
    __syncthreads();
    if (t == 0) {
        double sns = 0.0, snl = 0.0;
        for (int i = 0; i < 256; i++) { sns += dsig[i]; snl += dsp[i]; }
        float* scf = (float*)sc;
        unsigned np = sc[0];
        float psig = scf[1], plos = scf[2];
        double denom = (double)psig + sns + (double)np;
        double dice = 1.0 - (2.0 * (double)psig + (double)EPSF) / (denom + (double)EPSF);
        unsigned totsel = np + k;
        double mean = totsel ? (((double)plos + snl) / (double)totsel) : 0.0;
        out[0] = (float)(dice + mean);
    }
}

// ---------------------------------------------------------------------------
extern "C" void kernel_launch(void* const* d_in, const int* in_sizes, int n_in,
                              void* d_out, int out_size, void* d_ws, size_t ws_size,
                              hipStream_t stream) {
    const float* preds = (const float*)d_in[0];
    const int*   targs = (const int*)d_in[1];
    float* out = (float*)d_out;
    int N = in_sizes[0];

    unsigned* ws    = (unsigned*)d_ws;
    unsigned* sc    = ws + SC_OFF;
    float4*   bstat = (float4*)(ws + BSTAT_OFF);
    unsigned* rep   = ws + REP_OFF;
    unsigned* low   = ws + LOW_OFF;

    int nfull = N >> 13;
    int grid = nfull + ((N & 8191) ? 1 : 0);
    if (grid < 1) grid = 1;
    if (grid > 4096) grid = 4096;   // bstat bound; blocks grid-stride past

    zeroAll<<<64, 256, 0, stream>>>(ws, ZERO_WORDS);
    k1<<<grid, 256, 0, stream>>>(preds, targs, N, bstat, rep);
    flagK<<<1, 256, 0, stream>>>(bstat, grid, sc, (unsigned)N);
    lowH<<<512, 256, 0, stream>>>(preds, targs, N, sc, low);
    finalize<<<1, 256, 0, stream>>>(rep, low, sc, out);
}

// Round 12
// 168.313 us; speedup vs baseline: 1.1942x; 1.0091x over previous
//
#include <hip/hip_runtime.h>

#define EPSF 1e-10f

constexpr unsigned KEY15 = 0xBFC00000u;  // f2key(1.5f), bucket-aligned
constexpr int BUCK0 = 0xBFC;             // first tracked bucket (3068)
constexpr int NB2   = 4096 - BUCK0;      // 1028 tracked buckets
constexpr int NBKT  = 4096;
constexpr int NREP  = 8;                 // replica rows for flush

typedef float pf4 __attribute__((ext_vector_type(4)));
typedef int   pi4 __attribute__((ext_vector_type(4)));

// ---------- workspace layout (words) ----------
// sc: 0 np(u32) 1 psig(f32) 2 plos(f32) 3 k(u32) 7 flag(u32)
constexpr int SC_OFF    = 0;
constexpr int BSTAT_OFF = 64;                       // 4096 float4 (16384 words)
constexpr int REP_OFF   = BSTAT_OFF + 4096 * 4;     // 16448
constexpr int LOW_OFF   = REP_OFF + NREP * NB2;     // 24672 (fallback hist)
constexpr int ZERO_WORDS = LOW_OFF + NBKT;          // 28768

__device__ __forceinline__ float sigmoidf_(float x) {
    return 1.0f / (1.0f + expf(-x));
}
__device__ __forceinline__ float softplusf_(float x) {
    return fmaxf(x, 0.0f) + log1pf(expf(-fabsf(x)));
}
__device__ __forceinline__ unsigned f2key(float x) {
    unsigned b = __float_as_uint(x);
    return b ^ ((unsigned)((int)b >> 31) | 0x80000000u);
}
__device__ __forceinline__ float key2f(unsigned k) {
    unsigned b = (k & 0x80000000u) ? (k & 0x7FFFFFFFu) : ~k;
    return __uint_as_float(b);
}

// ---------------------------------------------------------------------------
__global__ void zeroAll(unsigned* ws, int nwords) {
    int stride = gridDim.x * blockDim.x;
    for (int i = blockIdx.x * blockDim.x + threadIdx.x; i < nwords; i += stride)
        ws[i] = 0u;
}

// K1: 8192 elements per block-tile. A SINGLE asm block issues 16 independent
// global_load_dwordx4 (early-clobber outputs -> 64 data VGPRs the allocator
// cannot recycle) then s_waitcnt vmcnt(0). Forces the MLP the compiler kept
// collapsing (rounds 8-10: VGPR pinned at 48). [round 11: removed k1 from
// top-5, total -31 us]
__global__ __launch_bounds__(256) void k1(const float* __restrict__ preds,
                                          const int* __restrict__ targs, int N,
                                          float4* __restrict__ bstat,
                                          unsigned* __restrict__ rep) {
    __shared__ int lh[NB2];
    for (int i = threadIdx.x; i < NB2; i += 256) lh[i] = 0;
    __syncthreads();

    float pc = 0.f, psig = 0.f, plos = 0.f;
    const int tid = threadIdx.x;
    const int lane = tid & 63;
    const int w = tid >> 6;

    int nfull = N >> 13;                     // full 8192-element tiles
    for (int grp = blockIdx.x; grp < nfull; grp += gridDim.x) {
        size_t ebase = ((size_t)grp << 13) + ((size_t)w << 11) + ((size_t)lane << 2);
        const float* pp  = preds + ebase;        // wave tile: 2048 elements
        const float* pp2 = pp + 1024;
        const int*   tp  = targs + ebase;
        const int*   tp2 = tp + 1024;
        pf4 P[8]; pi4 T[8];
        asm volatile(
            "global_load_dwordx4 %0, %16, off\n\t"
            "global_load_dwordx4 %1, %16, off offset:1024\n\t"
            "global_load_dwordx4 %2, %16, off offset:2048\n\t"
            "global_load_dwordx4 %3, %16, off offset:3072\n\t"
            "global_load_dwordx4 %4, %17, off\n\t"
            "global_load_dwordx4 %5, %17, off offset:1024\n\t"
            "global_load_dwordx4 %6, %17, off offset:2048\n\t"
            "global_load_dwordx4 %7, %17, off offset:3072\n\t"
            "global_load_dwordx4 %8, %18, off\n\t"
            "global_load_dwordx4 %9, %18, off offset:1024\n\t"
            "global_load_dwordx4 %10, %18, off offset:2048\n\t"
            "global_load_dwordx4 %11, %18, off offset:3072\n\t"
            "global_load_dwordx4 %12, %19, off\n\t"
            "global_load_dwordx4 %13, %19, off offset:1024\n\t"
            "global_load_dwordx4 %14, %19, off offset:2048\n\t"
            "global_load_dwordx4 %15, %19, off offset:3072\n\t"
            "s_waitcnt vmcnt(0)"
            : "=&v"(P[0]), "=&v"(P[1]), "=&v"(P[2]), "=&v"(P[3]),
              "=&v"(P[4]), "=&v"(P[5]), "=&v"(P[6]), "=&v"(P[7]),
              "=&v"(T[0]), "=&v"(T[1]), "=&v"(T[2]), "=&v"(T[3]),
              "=&v"(T[4]), "=&v"(T[5]), "=&v"(T[6]), "=&v"(T[7])
            : "v"(pp), "v"(pp2), "v"(tp), "v"(tp2)
            : "memory");
#pragma unroll
        for (int g = 0; g < 8; g++) {
            pf4 pv = P[g]; pi4 tv = T[g];
#pragma unroll
            for (int j = 0; j < 4; j++) {
                float x = pv[j];
                unsigned key = f2key(x);
                if ((tv[j] == 0) && (key >= KEY15))
                    atomicAdd(&lh[(key >> 20) - BUCK0], 1);   // fire-and-forget ds_add
            }
            if (tv[0] | tv[1] | tv[2] | tv[3]) {   // rare positive path
#pragma unroll
                for (int j = 0; j < 4; j++)
                    if (tv[j]) {
                        float x = pv[j];
                        pc += 1.f; psig += sigmoidf_(x); plos += softplusf_(x) - x;
                    }
            }
        }
    }
    // tail elements (N % 8192), last block only
    if (blockIdx.x == gridDim.x - 1) {
        for (int i = (nfull << 13) + tid; i < N; i += 256) {
            float x = preds[i];
            if (targs[i]) { pc += 1.f; psig += sigmoidf_(x); plos += softplusf_(x) - x; }
            else {
                unsigned key = f2key(x);
                if (key >= KEY15) atomicAdd(&lh[(key >> 20) - BUCK0], 1);
            }
        }
    }
    __syncthreads();
    // flush hist + accumulate this block's qualifying count
    float qc = 0.f;
    unsigned* my = rep + (unsigned)(blockIdx.x & (NREP - 1)) * NB2;
    for (int i = tid; i < NB2; i += 256) {
        int c = lh[i];
        if (c) { atomicAdd(&my[i], (unsigned)c); qc += (float)c; }
    }
#pragma unroll
    for (int o = 32; o > 0; o >>= 1) {
        pc   += __shfl_down(pc, o);
        psig += __shfl_down(psig, o);
        plos += __shfl_down(plos, o);
        qc   += __shfl_down(qc, o);
    }
    __shared__ float rp[4], rs[4], rl[4], rq[4];
    if ((tid & 63) == 0) { rp[w] = pc; rs[w] = psig; rl[w] = plos; rq[w] = qc; }
    __syncthreads();
    if (tid == 0)
        bstat[blockIdx.x] = make_float4(rp[0] + rp[1] + rp[2] + rp[3],
                                        rs[0] + rs[1] + rs[2] + rs[3],
                                        rl[0] + rl[1] + rl[2] + rl[3],
                                        rq[0] + rq[1] + rq[2] + rq[3]);
}

// flagK: reduce per-block stats (qualifying count in .w) -> np, psig, plos,
// k, fallback flag. Reads only bstat (64 KB).
__global__ void flagK(const float4* __restrict__ bstat, int nblocks,
                      unsigned* __restrict__ sc, unsigned N) {
    float pc = 0.f, ps = 0.f, pl = 0.f, qt = 0.f;
    for (int i = threadIdx.x; i < nblocks; i += 256) {
        float4 v = bstat[i];
        pc += v.x; ps += v.y; pl += v.z; qt += v.w;
    }
#pragma unroll
    for (int o = 32; o > 0; o >>= 1) {
        pc += __shfl_down(pc, o);
        ps += __shfl_down(ps, o);
        pl += __shfl_down(pl, o);
        qt += __shfl_down(qt, o);
    }
    __shared__ float rp[4], rs[4], rl[4], rq[4];
    int w = threadIdx.x >> 6;
    if ((threadIdx.x & 63) == 0) { rp[w] = pc; rs[w] = ps; rl[w] = pl; rq[w] = qt; }
    __syncthreads();
    if (threadIdx.x == 0) {
        unsigned np = (unsigned)(rp[0] + rp[1] + rp[2] + rp[3] + 0.5f);
        float psT = rs[0] + rs[1] + rs[2] + rs[3];
        float plT = rl[0] + rl[1] + rl[2] + rl[3];
        unsigned qtT = (unsigned)(rq[0] + rq[1] + rq[2] + rq[3] + 0.5f);
        unsigned nn = N - np;
        unsigned k = (np == 0u) ? (unsigned)(0.1 * (double)nn)
                                : ((30u * np < nn) ? 30u * np : nn);
        float* scf = (float*)sc;
        sc[0] = np; scf[1] = psT; scf[2] = plT; sc[3] = k;
        sc[7] = (k > qtT) ? 1u : 0u;
    }
}

// Fallback (flag only): histogram negatives with key < KEY15. Normally exits.
__global__ __launch_bounds__(256) void lowH(const float* __restrict__ preds,
                                            const int* __restrict__ targs, int N,
                                            const unsigned* __restrict__ sc,
                                            unsigned* __restrict__ low) {
    if (sc[7] == 0u) return;
    int gtid = blockIdx.x * 256 + threadIdx.x;
    int gstr = gridDim.x * 256;
    for (int i = gtid; i < N; i += gstr) {
        if (!targs[i]) {
            unsigned key = f2key(preds[i]);
            if (key < KEY15) atomicAdd(&low[key >> 20], 1u);
        }
    }
}

// finalize: counts = replicas (>= BUCK0, 2 independent accumulator chains for
// MLP on L3-latency reads) + low hist (< BUCK0, flag path); suffix-scan ->
// b1/r1; analytic bucket-midpoint sums reduced via WAVE SHUFFLE (round 11:
// the serial thread-0 loop over 256 LDS doubles was ~25 us of the 53 us).
__global__ void finalize(const unsigned* __restrict__ rep,
                         const unsigned* __restrict__ low,
                         unsigned* __restrict__ sc, float* __restrict__ out) {
    __shared__ unsigned sa[256], sb[256];
    __shared__ int sb1;
    __shared__ unsigned sr1;
    __shared__ double rds[4], rdl[4];
    int t = threadIdx.x;
    int base = t * 16;
    unsigned c[16]; unsigned tot = 0;
#pragma unroll
    for (int j = 0; j < 16; j++) {
        int b = base + j;
        unsigned s;
        if (b >= BUCK0) {
            int idx = b - BUCK0;
            unsigned s0 = 0, s1 = 0;   // two chains -> 2x loads in flight
#pragma unroll
            for (int r = 0; r < NREP; r += 2) {
                s0 += rep[r * NB2 + idx];
                s1 += rep[(r + 1) * NB2 + idx];
            }
            s = s0 + s1;
        } else {
            s = low[b];
        }
        c[j] = s; tot += s;
    }
    sa[t] = tot;
    if (t == 0) { sb1 = NBKT; sr1 = 0u; }
    __syncthreads();
    unsigned k = sc[3];
    unsigned* src = sa; unsigned* dst = sb;
    for (int off = 1; off < 256; off <<= 1) {
        unsigned v = src[t] + ((t + off < 256) ? src[t + off] : 0u);
        dst[t] = v;
        __syncthreads();
        unsigned* tmp = src; src = dst; dst = tmp;
    }
    if (k > 0u) {
        unsigned above = src[t] - tot;
        if (above < k && above + tot >= k) {
            unsigned cum = above;
            for (int j = 15; j >= 0; j--) {
                unsigned cc = c[j];
                if (cum + cc >= k) { sb1 = base + j; sr1 = k - cum; break; }
                cum += cc;
            }
        }
    }
    __syncthreads();
    int b1 = sb1; unsigned r1 = sr1;
    double ssig = 0.0, ssp = 0.0;
#pragma unroll
    for (int j = 0; j < 16; j++) {
        int b = base + j; unsigned cc = c[j];
        if (cc == 0u) continue;
        bool full = (b > b1);
        bool part = (b == b1) && (r1 > 0u);
        if (!(full || part)) continue;
        float lo = key2f((unsigned)b << 20);
        float hi = (b == NBKT - 1) ? key2f(0xFF7FFFFFu)
                                   : key2f(((unsigned)(b + 1)) << 20);
        if (full) {
            float mid = 0.5f * (lo + hi);
            ssig += (double)cc * (double)sigmoidf_(mid);
            ssp  += (double)cc * (double)softplusf_(mid);
        } else {
            unsigned take = (r1 < cc) ? r1 : cc;
            double q = (double)take / (double)cc;
            float rp = (float)((double)hi - 0.5 * q * ((double)hi - (double)lo));
            ssig += (double)take * (double)sigmoidf_(rp);
            ssp  += (double)take * (double)softplusf_(rp);
        }
    }
    // wave shuffle reduce + 4-slot cross-wave combine (replaces 256-iter
    // serial thread-0 LDS loop)
#pragma unroll
    for (int o = 32; o > 0; o >>= 1) {
        ssig += __shfl_down(ssig, o);
        ssp  += __shfl_down(ssp, o);
    }
    int w = t >> 6;
    if ((t & 63) == 0) { rds[w] = ssig; rdl[w] = ssp; }
    __syncthreads();
    if (t == 0) {
        double sns = rds[0] + rds[1] + rds[2] + rds[3];
        double snl = rdl[0] + rdl[1] + rdl[2] + rdl[3];
        float* scf = (float*)sc;
        unsigned np = sc[0];
        float psig = scf[1], plos = scf[2];
        double denom = (double)psig + sns + (double)np;
        double dice = 1.0 - (2.0 * (double)psig + (double)EPSF) / (denom + (double)EPSF);
        unsigned totsel = np + k;
        double mean = totsel ? (((double)plos + snl) / (double)totsel) : 0.0;
        out[0] = (float)(dice + mean);
    }
}

// ---------------------------------------------------------------------------
extern "C" void kernel_launch(void* const* d_in, const int* in_sizes, int n_in,
                              void* d_out, int out_size, void* d_ws, size_t ws_size,
                              hipStream_t stream) {
    const float* preds = (const float*)d_in[0];
    const int*   targs = (const int*)d_in[1];
    float* out = (float*)d_out;
    int N = in_sizes[0];

    unsigned* ws    = (unsigned*)d_ws;
    unsigned* sc    = ws + SC_OFF;
    float4*   bstat = (float4*)(ws + BSTAT_OFF);
    unsigned* rep   = ws + REP_OFF;
    unsigned* low   = ws + LOW_OFF;

    int nfull = N >> 13;
    int grid = nfull + ((N & 8191) ? 1 : 0);
    if (grid < 1) grid = 1;
    if (grid > 4096) grid = 4096;   // bstat bound; blocks grid-stride past

    zeroAll<<<64, 256, 0, stream>>>(ws, ZERO_WORDS);
    k1<<<grid, 256, 0, stream>>>(preds, targs, N, bstat, rep);
    flagK<<<1, 256, 0, stream>>>(bstat, grid, sc, (unsigned)N);
    lowH<<<512, 256, 0, stream>>>(preds, targs, N, sc, low);
    finalize<<<1, 256, 0, stream>>>(rep, low, sc, out);
}